// Round 5
// baseline (132.684 us; speedup 1.0000x reference)
//
#include <hip/hip_runtime.h>
#include <stdint.h>

typedef __bf16 bf16;
typedef bf16 bf16x8 __attribute__((ext_vector_type(8)));
typedef float floatx4 __attribute__((ext_vector_type(4)));

#define INV_T 2.0f                        // 1 / TEMPERATURE
#define EXP2_SCALE 2.8853900817779268f    // INV_T * log2(e)

// ---------------------------------------------------------------------------
// Kernel 1: L2-normalize each row of proj_1 / proj_2 (fp32), write bf16 reps.
// ---------------------------------------------------------------------------
__global__ __launch_bounds__(256) void nrm_kernel(const float* __restrict__ p1,
                                                  const float* __restrict__ p2,
                                                  unsigned* __restrict__ reps) {
    int gt   = blockIdx.x * 256 + threadIdx.x;
    int row  = gt >> 6;
    int lane = gt & 63;
    const float* srcRow = (row < 4096) ? (p1 + (size_t)row * 128)
                                       : (p2 + (size_t)(row - 4096) * 128);
    float2 v = ((const float2*)srcRow)[lane];
    float ss = v.x * v.x + v.y * v.y;
#pragma unroll
    for (int s = 1; s < 64; s <<= 1) ss += __shfl_xor(ss, s, 64);
    float inv = 1.0f / fmaxf(sqrtf(ss), 1e-12f);
    union { bf16 h[2]; unsigned u; } pk;
    pk.h[0] = (bf16)(v.x * inv);
    pk.h[1] = (bf16)(v.y * inv);
    reps[(size_t)row * 64 + lane] = pk.u;   // row-major [8192][128] bf16
}

// ---------------------------------------------------------------------------
// Kernel 2: rowsum partials + positive-pair dot.
// B tiles staged through LDS (coalesced 1KB global loads), XOR-swizzled 16B
// chunks so B-frag ds_read_b128 is <=2-way bank aliased (free, m136), and
// single-barrier ping-pong double buffering so tile cj+1's global loads are
// in flight across tile cj's MFMA+exp processing. A-frags direct from global
// (once per block). Grid (8 col-groups, 64 row-tiles), block 256 = 4 waves.
// LDS = 2 x 32 KB -> 2 blocks/CU.
// ---------------------------------------------------------------------------
__global__ __launch_bounds__(256, 2) void sim_kernel(const bf16* __restrict__ reps,
                                                     float* __restrict__ rowsum16,
                                                     float* __restrict__ pos) {
    // lB[buf][row*16 + (chunk ^ (row&7))], chunk = 16B unit of the 256B row
    __shared__ uint4 lB[2][128 * 16];   // 64 KB

    const int cg   = blockIdx.x;   // 0..7
    const int bi   = blockIdx.y;   // 0..63
    const int tid  = threadIdx.x;
    const int w    = tid >> 6;     // wave 0..3
    const int lane = tid & 63;
    const int quad = lane >> 4;
    const int lcol = lane & 15;

    const int rowTileBase = bi * 128;
    const int wRow = (w >> 1) * 64;
    const int wCol = (w & 1) * 64;

    // A fragments straight from global, constant across all B tiles.
    // lane holds A[m = lcol][k = quad*8 + j] -> 16B contiguous slice of a row
    bf16x8 aF[4][4];
    const bf16* aBase = reps + (size_t)(rowTileBase + wRow + lcol) * 128 + quad * 8;
#pragma unroll
    for (int mi = 0; mi < 4; mi++)
#pragma unroll
        for (int ks = 0; ks < 4; ks++)
            aF[mi][ks] = *(const bf16x8*)(aBase + mi * 2048 + ks * 32);

    float rs[16];   // per-lane rowsum partials, index = mi*4 + reg
#pragma unroll
    for (int i = 0; i < 16; i++) rs[i] = 0.0f;

    // stage B tile 0
    {
        const uint4* g = (const uint4*)(reps + (size_t)(cg * 1024) * 128);
#pragma unroll
        for (int i = 0; i < 8; i++) {
            int p = i * 256 + tid;                 // flat 16B-chunk index
            int row = p >> 4, ch = p & 15;
            lB[0][row * 16 + (ch ^ (row & 7))] = g[p];
        }
    }
    __syncthreads();

    int cur = 0;
    for (int cj = 0; cj < 8; cj++) {
        // prefetch tile cj+1 into registers (coalesced, overlaps processing)
        uint4 st[8];
        if (cj < 7) {
            const uint4* g = (const uint4*)(reps + (size_t)(cg * 1024 + (cj + 1) * 128) * 128);
#pragma unroll
            for (int i = 0; i < 8; i++) st[i] = g[i * 256 + tid];
        }

        const int colTileBase = cg * 1024 + cj * 128;
        const bool diagT = (colTileBase == rowTileBase);
        const bool partT = (colTileBase == ((rowTileBase + 4096) & 8191));

#pragma unroll
        for (int ni = 0; ni < 4; ni++) {
            const int cl = wCol + ni * 16 + lcol;   // col within tile
            bf16x8 bF[4];
#pragma unroll
            for (int ks = 0; ks < 4; ks++)
                bF[ks] = *(const bf16x8*)&lB[cur][cl * 16 + ((ks * 4 + quad) ^ (cl & 7))];

            floatx4 acc[4];
            const floatx4 zf = {0.0f, 0.0f, 0.0f, 0.0f};
#pragma unroll
            for (int mi = 0; mi < 4; mi++) acc[mi] = zf;
#pragma unroll
            for (int ks = 0; ks < 4; ks++)
#pragma unroll
                for (int mi = 0; mi < 4; mi++)
                    acc[mi] = __builtin_amdgcn_mfma_f32_16x16x32_bf16(
                        aF[mi][ks], bF[ks], acc[mi], 0, 0, 0);

            // fused epilogue for this 64(row) x 16(col) strip
            const int gcol = colTileBase + cl;
            if (diagT | partT) {
#pragma unroll
                for (int mi = 0; mi < 4; mi++)
#pragma unroll
                    for (int r = 0; r < 4; r++) {
                        int grow = rowTileBase + wRow + mi * 16 + quad * 4 + r;
                        float s = acc[mi][r];
                        if (partT && gcol == ((grow + 4096) & 8191)) pos[grow] = s;
                        float e = __builtin_amdgcn_exp2f(s * EXP2_SCALE);
                        if (diagT && grow == gcol) e = 0.0f;   // mask j == i
                        rs[mi * 4 + r] += e;
                    }
            } else {
#pragma unroll
                for (int mi = 0; mi < 4; mi++)
#pragma unroll
                    for (int r = 0; r < 4; r++)
                        rs[mi * 4 + r] += __builtin_amdgcn_exp2f(acc[mi][r] * EXP2_SCALE);
            }
        }

        // write prefetched tile into the other buffer, then one barrier
        if (cj < 7) {
#pragma unroll
            for (int i = 0; i < 8; i++) {
                int p = i * 256 + tid;
                int row = p >> 4, ch = p & 15;
                lB[cur ^ 1][row * 16 + (ch ^ (row & 7))] = st[i];
            }
        }
        __syncthreads();
        cur ^= 1;
    }

    // sum over the 16 columns handled per quad: reduce across lane bits 0-3
#pragma unroll
    for (int s = 1; s < 16; s <<= 1)
#pragma unroll
        for (int k = 0; k < 16; k++) rs[k] += __shfl_xor(rs[k], s, 64);

    if (lcol == 0) {
        float* dst = rowsum16 + (size_t)(cg * 2 + (w & 1)) * 8192;
#pragma unroll
        for (int k = 0; k < 16; k++) {
            int grow = rowTileBase + wRow + (k >> 2) * 16 + quad * 4 + (k & 3);
            dst[grow] = rs[k];   // unique slot, written exactly once
        }
    }
}

// ---------------------------------------------------------------------------
// Kernel 3: loss = (1/8192) * sum_i [ log(sum_p rowsum16[p][i]) - 2*pos_i ]
// ---------------------------------------------------------------------------
__global__ __launch_bounds__(1024) void fin_kernel(const float* __restrict__ rowsum16,
                                                   const float* __restrict__ pos,
                                                   float* __restrict__ out) {
    float v = 0.0f;
#pragma unroll
    for (int rr = 0; rr < 8; rr++) {
        int r = rr * 1024 + threadIdx.x;
        float d = 0.0f;
#pragma unroll
        for (int p = 0; p < 16; p++) d += rowsum16[p * 8192 + r];
        v += logf(d) - pos[r] * INV_T;
    }
#pragma unroll
    for (int s = 1; s < 64; s <<= 1) v += __shfl_xor(v, s, 64);
    __shared__ float red[16];
    if ((threadIdx.x & 63) == 0) red[threadIdx.x >> 6] = v;
    __syncthreads();
    if (threadIdx.x == 0) {
        float t = 0.0f;
#pragma unroll
        for (int i = 0; i < 16; i++) t += red[i];
        *out = t * (1.0f / 8192.0f);
    }
}

extern "C" void kernel_launch(void* const* d_in, const int* in_sizes, int n_in,
                              void* d_out, int out_size, void* d_ws, size_t ws_size,
                              hipStream_t stream) {
    const float* p1 = (const float*)d_in[0];
    const float* p2 = (const float*)d_in[1];
    float* out = (float*)d_out;

    char* ws        = (char*)d_ws;
    bf16* reps      = (bf16*)ws;                                // 2 MB
    float* rowsum16 = (float*)(ws + (2u << 20));                // 512 KB
    float* pos      = (float*)(ws + (2u << 20) + (512u << 10)); // 32 KB

    nrm_kernel<<<2048, 256, 0, stream>>>(p1, p2, (unsigned*)reps);
    sim_kernel<<<dim3(8, 64), 256, 0, stream>>>(reps, rowsum16, pos);
    fin_kernel<<<1, 1024, 0, stream>>>(rowsum16, pos, out);
}

// Round 6
// 91.246 us; speedup vs baseline: 1.4541x; 1.4541x over previous
//
#include <hip/hip_runtime.h>
#include <stdint.h>

typedef __bf16 bf16;
typedef bf16 bf16x8 __attribute__((ext_vector_type(8)));
typedef float floatx4 __attribute__((ext_vector_type(4)));

#define INV_T     2.0f                      // 1 / TEMPERATURE
#define SQRT_K    1.6986436206f             // sqrt(INV_T * log2(e))
#define INV_K     0.34657359028f            // ln(2)/2 = 1/(INV_T*log2(e))
#define GLOBAL_AS __attribute__((address_space(1)))
#define LDS_AS    __attribute__((address_space(3)))

// rep2 layout (16B chunks): chunk(r, ch) = (r>>6)*1024 + ch*64 + (r&63),
// ch = k>>3. Makes MFMA A/B fragment loads and tile staging fully coalesced,
// and LDS fragment reads structurally conflict-free.

// ---------------------------------------------------------------------------
// Kernel 1: L2-normalize rows, scale by SQRT_K, write bf16 rep2 (swizzled).
// One wave per row (128 f32 -> 2/lane). Thread 0 zeroes the output scalar.
// ---------------------------------------------------------------------------
__global__ __launch_bounds__(256) void nrm_kernel(const float* __restrict__ p1,
                                                  const float* __restrict__ p2,
                                                  uint32_t* __restrict__ rep2,
                                                  float* __restrict__ out) {
    int gt   = blockIdx.x * 256 + threadIdx.x;
    int row  = gt >> 6;
    int lane = gt & 63;
    const float* srcRow = (row < 4096) ? (p1 + (size_t)row * 128)
                                       : (p2 + (size_t)(row - 4096) * 128);
    float2 v = ((const float2*)srcRow)[lane];
    float ss = v.x * v.x + v.y * v.y;
#pragma unroll
    for (int s = 1; s < 64; s <<= 1) ss += __shfl_xor(ss, s, 64);
    float inv = SQRT_K / fmaxf(sqrtf(ss), 1e-12f);
    union { bf16 h[2]; uint32_t u; } pk;
    pk.h[0] = (bf16)(v.x * inv);
    pk.h[1] = (bf16)(v.y * inv);
    // lane holds k = 2*lane, 2*lane+1 -> chunk ch = lane>>2, dword = lane&3
    int chunk = (row >> 6) * 1024 + (lane >> 2) * 64 + (row & 63);
    rep2[chunk * 4 + (lane & 3)] = pk.u;
    if (gt == 0) *out = 0.0f;
}

// ---------------------------------------------------------------------------
// Kernel 2: rowsum partials + positive-pair dot.
// Grid (32 col-chunks x 32 row-blocks) = 1024 blocks, 256 thr = 4 waves.
// Block: 256 rows x 256 cols; wave w: rows [rb*256+w*64, +64), all 256 cols.
// B staged via async global_load_lds into 2x16KB LDS dbuf (4 tiles of 64
// cols, 1 barrier each). A-frags coalesced from rep2, held in registers.
// acc = K * dot (operands pre-scaled by sqrt(K)) -> exp2(acc) directly.
// ---------------------------------------------------------------------------
__global__ __launch_bounds__(256, 3) void sim_kernel(const uint4* __restrict__ rep2,
                                                     float* __restrict__ rowsumP,
                                                     float* __restrict__ pos) {
    __shared__ uint4 lB[2][1024];   // 2 x 16 KB

    const int cc   = blockIdx.x;   // col chunk: cols [cc*256, +256)
    const int rb   = blockIdx.y;   // row block: rows [rb*256, +256)
    const int tid  = threadIdx.x;
    const int w    = tid >> 6;
    const int lane = tid & 63;
    const int quad = lane >> 4;
    const int lcol = lane & 15;

    const int wbase = rb * 256 + w * 64;   // wave's rows (64-aligned)
    const int pbase = (wbase + 4096) & 8191; // partner col block (64-aligned)

    // A fragments: aF[mi][ks] = rows wbase+mi*16+lcol, k = ks*32+quad*8..+7
    bf16x8 aF[4][4];
    const uint4* aG = rep2 + (size_t)(wbase >> 6) * 1024;
#pragma unroll
    for (int mi = 0; mi < 4; mi++)
#pragma unroll
        for (int ks = 0; ks < 4; ks++)
            aF[mi][ks] = *(const bf16x8*)&aG[(ks * 4 + quad) * 64 + mi * 16 + lcol];

    float rs[16];
#pragma unroll
    for (int i = 0; i < 16; i++) rs[i] = 0.0f;

    // stage tile 0 (cols cc*256..+63): contiguous 1024 chunks in rep2
    {
        const uint4* src = rep2 + (size_t)(cc * 4) * 1024;
#pragma unroll
        for (int j = 0; j < 4; j++)
            __builtin_amdgcn_global_load_lds(
                (const GLOBAL_AS uint32_t*)(src + j * 256 + tid),
                (LDS_AS uint32_t*)&lB[0][j * 256 + tid], 16, 0, 0);
    }
    __syncthreads();

    for (int t = 0; t < 4; t++) {
        const int cur = t & 1;
        if (t < 3) {   // async-prefetch next tile into the other buffer
            const uint4* src = rep2 + (size_t)(cc * 4 + t + 1) * 1024;
#pragma unroll
            for (int j = 0; j < 4; j++)
                __builtin_amdgcn_global_load_lds(
                    (const GLOBAL_AS uint32_t*)(src + j * 256 + tid),
                    (LDS_AS uint32_t*)&lB[cur ^ 1][j * 256 + tid], 16, 0, 0);
        }

        const int c0t = cc * 256 + t * 64;
#pragma unroll
        for (int so = 0; so < 4; so++) {
            bf16x8 bF[4];
#pragma unroll
            for (int ks = 0; ks < 4; ks++)
                bF[ks] = *(const bf16x8*)&lB[cur][(ks * 4 + quad) * 64 + so * 16 + lcol];

            floatx4 acc[4];
            const floatx4 zf = {0.0f, 0.0f, 0.0f, 0.0f};
#pragma unroll
            for (int mi = 0; mi < 4; mi++) acc[mi] = zf;
#pragma unroll
            for (int ks = 0; ks < 4; ks++)
#pragma unroll
                for (int mi = 0; mi < 4; mi++)
                    acc[mi] = __builtin_amdgcn_mfma_f32_16x16x32_bf16(
                        aF[mi][ks], bF[ks], acc[mi], 0, 0, 0);

            const int c0s  = c0t + so * 16;
            const int gcol = c0s + lcol;
            const bool diagS = ((c0s & ~63) == wbase);
            const bool partS = ((c0s & ~63) == pbase);
            if (diagS | partS) {
#pragma unroll
                for (int mi = 0; mi < 4; mi++)
#pragma unroll
                    for (int r = 0; r < 4; r++) {
                        int grow = wbase + mi * 16 + quad * 4 + r;
                        float s = acc[mi][r];
                        if (partS && gcol == ((grow + 4096) & 8191))
                            pos[grow] = s * INV_K;   // recover raw dot
                        float e = __builtin_amdgcn_exp2f(s);
                        if (diagS && grow == gcol) e = 0.0f;   // mask j == i
                        rs[mi * 4 + r] += e;
                    }
            } else {
#pragma unroll
                for (int mi = 0; mi < 4; mi++)
#pragma unroll
                    for (int r = 0; r < 4; r++)
                        rs[mi * 4 + r] += __builtin_amdgcn_exp2f(acc[mi][r]);
            }
        }
        __syncthreads();   // drains prefetch + releases cur for overwrite
    }

    // reduce across the 16 cols per quad (lane bits 0-3)
#pragma unroll
    for (int s = 1; s < 16; s <<= 1)
#pragma unroll
        for (int k = 0; k < 16; k++) rs[k] += __shfl_xor(rs[k], s, 64);

    if (lcol == 0) {
#pragma unroll
        for (int k = 0; k < 16; k++) {
            int grow = wbase + (k >> 2) * 16 + quad * 4 + (k & 3);
            rowsumP[(size_t)grow * 32 + cc] = rs[k];   // unique slot
        }
    }
}

// ---------------------------------------------------------------------------
// Kernel 3: loss = (1/8192) * sum_i [ log(sum_c rowsumP[i][c]) - 2*pos_i ]
// 64 blocks x 128 threads (1 row/thread); out zero-initialized by nrm_kernel.
// ---------------------------------------------------------------------------
__global__ __launch_bounds__(128) void fin_kernel(const float* __restrict__ rowsumP,
                                                  const float* __restrict__ pos,
                                                  float* __restrict__ out) {
    int row = blockIdx.x * 128 + threadIdx.x;
    const floatx4* rp = (const floatx4*)(rowsumP + (size_t)row * 32);
    float d = 0.0f;
#pragma unroll
    for (int j = 0; j < 8; j++) {
        floatx4 q = rp[j];
        d += (q[0] + q[1]) + (q[2] + q[3]);
    }
    float v = logf(d) - pos[row] * INV_T;
#pragma unroll
    for (int s = 1; s < 64; s <<= 1) v += __shfl_xor(v, s, 64);
    __shared__ float red[2];
    if ((threadIdx.x & 63) == 0) red[threadIdx.x >> 6] = v;
    __syncthreads();
    if (threadIdx.x == 0)
        atomicAdd(out, (red[0] + red[1]) * (1.0f / 8192.0f));
}

extern "C" void kernel_launch(void* const* d_in, const int* in_sizes, int n_in,
                              void* d_out, int out_size, void* d_ws, size_t ws_size,
                              hipStream_t stream) {
    const float* p1 = (const float*)d_in[0];
    const float* p2 = (const float*)d_in[1];
    float* out = (float*)d_out;

    char* ws       = (char*)d_ws;
    uint32_t* rep2 = (uint32_t*)ws;                             // 2 MB
    float* rowsumP = (float*)(ws + (2u << 20));                 // 1 MB
    float* pos     = (float*)(ws + (3u << 20));                 // 32 KB

    nrm_kernel<<<2048, 256, 0, stream>>>(p1, p2, rep2, out);
    sim_kernel<<<dim3(32, 32), 256, 0, stream>>>((const uint4*)rep2, rowsumP, pos);
    fin_kernel<<<64, 128, 0, stream>>>(rowsumP, pos, out);
}